// Round 1
// baseline (22111.235 us; speedup 1.0000x reference)
//
#include <hip/hip_runtime.h>
#include <math.h>
#include <type_traits>

#define BS   4
#define QLEN 2048
#define DIM  1024
#define NH   16
#define DH   64

// =====================================================================
// Kernel 1: projection GEMM  Out = (X @ W^T + bias) * scale
//   X: [8192,1024] row-major, W: [1024,1024] row-major (out-feature major)
//   Output written in [b, h, s, dh] layout for the attention kernel.
//   F64: accumulate in double (precision-critical Q/K path).
// =====================================================================
#define GBM 64
#define GBN 64
#define GBK 32

template<bool F64>
__global__ __launch_bounds__(256)
void qkv_gemm(const float* __restrict__ X, const float* __restrict__ W,
              const float* __restrict__ bias, float* __restrict__ Out,
              float scale)
{
    using acc_t = typename std::conditional<F64, double, float>::type;
    __shared__ float xs[GBM][GBK + 1];   // +1 pad: conflict-free micro-tile reads
    __shared__ float wsm[GBN][GBK + 1];

    const int m0 = blockIdx.y * GBM;
    const int n0 = blockIdx.x * GBN;
    const int tid = threadIdx.x;
    const int tx = tid & 15, ty = tid >> 4;

    acc_t acc[4][4];
    #pragma unroll
    for (int i = 0; i < 4; ++i)
        #pragma unroll
        for (int j = 0; j < 4; ++j) acc[i][j] = (acc_t)0;

    for (int k0 = 0; k0 < DIM; k0 += GBK) {
        #pragma unroll
        for (int p = 0; p < 2; ++p) {
            int f4 = tid + p * 256;            // 512 float4 per tile
            int row = f4 >> 3;                 // 8 float4 per 32-float row
            int c4 = (f4 & 7) << 2;
            float4 xv = *(const float4*)&X[(size_t)(m0 + row) * DIM + k0 + c4];
            xs[row][c4] = xv.x; xs[row][c4+1] = xv.y; xs[row][c4+2] = xv.z; xs[row][c4+3] = xv.w;
            float4 wv = *(const float4*)&W[(size_t)(n0 + row) * DIM + k0 + c4];
            wsm[row][c4] = wv.x; wsm[row][c4+1] = wv.y; wsm[row][c4+2] = wv.z; wsm[row][c4+3] = wv.w;
        }
        __syncthreads();
        #pragma unroll
        for (int kk = 0; kk < GBK; ++kk) {
            float a[4], bb[4];
            #pragma unroll
            for (int i = 0; i < 4; ++i) a[i] = xs[ty * 4 + i][kk];
            #pragma unroll
            for (int j = 0; j < 4; ++j) bb[j] = wsm[tx * 4 + j][kk];
            if (F64) {
                #pragma unroll
                for (int i = 0; i < 4; ++i)
                    #pragma unroll
                    for (int j = 0; j < 4; ++j)
                        acc[i][j] = (acc_t)fma((double)a[i], (double)bb[j], (double)acc[i][j]);
            } else {
                #pragma unroll
                for (int i = 0; i < 4; ++i)
                    #pragma unroll
                    for (int j = 0; j < 4; ++j)
                        acc[i][j] = (acc_t)fmaf(a[i], bb[j], (float)acc[i][j]);
            }
        }
        __syncthreads();
    }

    // epilogue: bias + scale, write in [b,h,s,dh] layout
    #pragma unroll
    for (int i = 0; i < 4; ++i) {
        int row = m0 + ty * 4 + i;
        int b_ = row >> 11;          // / 2048
        int s_ = row & 2047;
        int col0 = n0 + tx * 4;
        int h_ = col0 >> 6, d_ = col0 & 63;
        float4 o;
        #pragma unroll
        for (int j = 0; j < 4; ++j) {
            acc_t v = (acc[i][j] + (acc_t)bias[col0 + j]) * (acc_t)scale;
            (&o.x)[j] = (float)v;
        }
        *(float4*)&Out[((size_t)((b_ * NH + h_) * QLEN + s_)) * DH + d_] = o;
    }
}

// =====================================================================
// Kernel 2: fused attention core.
//   One block = (batch b, 16 query rows), 512 threads = (q 0..15) x (kt 0..31).
//   Loops all 16 heads; per head: pass1 online (max, sumexp) streaming K
//   through LDS chunks of 128 rows, reduce, pass2 recompute scores ->
//   weights -> PV; ctx written to global (reuses d_out's out region).
//   Head-summed weights accumulated in f64 regs -> argmax (first-index ties).
// =====================================================================
#define QT  16
#define KC  128
#define NCH (QLEN / KC)   // 16

__global__ __launch_bounds__(512, 2)
void attn_kernel(const float* __restrict__ Qm, const float* __restrict__ Km,
                 const float* __restrict__ Vm, const int* __restrict__ mask,
                 float* __restrict__ ctx_out, float* __restrict__ idx_out)
{
    __shared__ float qs[QT][DH];                  //  4 KB
    __shared__ float ks[KC][DH + 1];              // 33 KB (+1: conflict-free score reads)
    __shared__ float vs[KC][DH];                  // 32 KB (lane-varies-d -> no pad needed)
    __shared__ __align__(8) float wch[QT][KC];    //  8 KB weights; overlaid reduce scratch
    __shared__ int   msk[KC];
    __shared__ float mq[QT];
    __shared__ float Lq[QT];

    double* dred = (double*)&wch[0][0];           // 512 doubles  @ [0,4096)
    float*  fred = (float*)&wch[8][0];            // 512 floats   @ [4096,6144)
    int*    ired = (int*)&wch[8][0];              // argmax idx overlay

    const int b   = blockIdx.y;
    const int q0  = blockIdx.x * QT;
    const int tid = threadIdx.x;
    const int q   = tid >> 5;        // 0..15
    const int kt  = tid & 31;        // 0..31

    // head-summed softmax weights, thread slot r=(c*4+jj) -> k = c*128 + jj*32 + kt
    double asum[64];
    #pragma unroll
    for (int r = 0; r < 64; ++r) asum[r] = 0.0;

    #pragma unroll 1
    for (int h = 0; h < NH; ++h) {
        const float* Qh = Qm + (((size_t)b * NH + h) * QLEN + q0) * DH;
        const float* Kh = Km + ((size_t)b * NH + h) * QLEN * DH;
        const float* Vh = Vm + ((size_t)b * NH + h) * QLEN * DH;

        {   // stage q-tile 16x64 (already includes 1/sqrt(dh))
            int i2 = tid << 1;
            int row = i2 >> 6, col = i2 & 63;
            *(float2*)&qs[row][col] = *(const float2*)&Qh[(size_t)row * DH + col];
        }

        // ---------------- pass 1: per-row running (max, sumexp) ----------------
        float  m = -INFINITY;
        double l = 0.0;
        #pragma unroll 1
        for (int c = 0; c < NCH; ++c) {
            #pragma unroll
            for (int p = 0; p < 4; ++p) {
                int f4 = tid + p * 512;
                int row = f4 >> 4, c4 = (f4 & 15) << 2;
                float4 kv = *(const float4*)&Kh[(size_t)(c * KC + row) * DH + c4];
                ks[row][c4] = kv.x; ks[row][c4+1] = kv.y; ks[row][c4+2] = kv.z; ks[row][c4+3] = kv.w;
            }
            if (tid < KC) msk[tid] = mask[b * QLEN + c * KC + tid];
            __syncthreads();

            float sacc[4] = {0.f, 0.f, 0.f, 0.f};
            #pragma unroll
            for (int d0 = 0; d0 < DH; d0 += 8) {
                float qr[8];
                #pragma unroll
                for (int dd = 0; dd < 8; ++dd) qr[dd] = qs[q][d0 + dd];
                #pragma unroll
                for (int jj = 0; jj < 4; ++jj)
                    #pragma unroll
                    for (int dd = 0; dd < 8; ++dd)
                        sacc[jj] = fmaf(qr[dd], ks[kt + 32 * jj][d0 + dd], sacc[jj]);
            }
            #pragma unroll
            for (int jj = 0; jj < 4; ++jj) {
                float s = msk[kt + 32 * jj] ? sacc[jj] : -INFINITY;
                if (s > m)              { l = l * (double)__expf(m - s) + 1.0; m = s; }
                else if (s > -INFINITY) { l += (double)__expf(s - m); }
            }
            __syncthreads();
        }

        // reduce (m,l) across the 32 kt-threads of each q-row
        dred[q * 32 + kt] = l;
        fred[q * 32 + kt] = m;
        __syncthreads();
        if (kt == 0) {
            float M = -INFINITY;
            for (int i = 0; i < 32; ++i) M = fmaxf(M, fred[q * 32 + i]);
            double L = 0.0;
            for (int i = 0; i < 32; ++i) {
                float mi = fred[q * 32 + i];
                if (mi > -INFINITY) L += dred[q * 32 + i] * exp((double)(mi - M));
            }
            mq[q] = M;
            Lq[q] = (float)L;
        }
        __syncthreads();

        // ---------------- pass 2: weights -> asum (f64) -> PV ----------------
        float cv0 = 0.f, cv1 = 0.f;
        const float Mv = mq[q], Lv = Lq[q];
        #pragma unroll
        for (int c = 0; c < NCH; ++c) {
            #pragma unroll
            for (int p = 0; p < 4; ++p) {
                int f4 = tid + p * 512;
                int row = f4 >> 4, c4 = (f4 & 15) << 2;
                float4 kv = *(const float4*)&Kh[(size_t)(c * KC + row) * DH + c4];
                ks[row][c4] = kv.x; ks[row][c4+1] = kv.y; ks[row][c4+2] = kv.z; ks[row][c4+3] = kv.w;
                *(float4*)&vs[row][c4] = *(const float4*)&Vh[(size_t)(c * KC + row) * DH + c4];
            }
            if (tid < KC) msk[tid] = mask[b * QLEN + c * KC + tid];
            __syncthreads();

            float sacc[4] = {0.f, 0.f, 0.f, 0.f};
            #pragma unroll
            for (int d0 = 0; d0 < DH; d0 += 8) {
                float qr[8];
                #pragma unroll
                for (int dd = 0; dd < 8; ++dd) qr[dd] = qs[q][d0 + dd];
                #pragma unroll
                for (int jj = 0; jj < 4; ++jj)
                    #pragma unroll
                    for (int dd = 0; dd < 8; ++dd)
                        sacc[jj] = fmaf(qr[dd], ks[kt + 32 * jj][d0 + dd], sacc[jj]);
            }
            #pragma unroll
            for (int jj = 0; jj < 4; ++jj) {
                float s = msk[kt + 32 * jj] ? sacc[jj] : -INFINITY;
                float w = expf(s - Mv) / Lv;          // accurate exp + true division
                wch[q][kt + 32 * jj] = w;
                asum[c * 4 + jj] += (double)w;        // static index: c-loop fully unrolled
            }
            __syncthreads();

            #pragma unroll 8
            for (int k = 0; k < KC; ++k) {
                float w = wch[q][k];
                cv0 = fmaf(w, vs[k][kt],      cv0);
                cv1 = fmaf(w, vs[k][kt + 32], cv1);
            }
            __syncthreads();
        }
        float* cp = ctx_out + ((size_t)(b * QLEN + q0 + q)) * DIM + h * DH;
        cp[kt]      = cv0;
        cp[kt + 32] = cv1;
    }

    // ---------------- argmax of head-summed weights (first-index ties) ------
    double bv = -1.0; int bk_ = 0;
    #pragma unroll
    for (int r = 0; r < 64; ++r) {   // k strictly increasing in r -> '>' keeps first
        int k = (r >> 2) * KC + (r & 3) * 32 + kt;
        if (asum[r] > bv) { bv = asum[r]; bk_ = k; }
    }
    __syncthreads();
    dred[q * 32 + kt] = bv;
    ired[q * 32 + kt] = bk_;
    __syncthreads();
    if (kt == 0) {
        double BV = -1.0; int BKi = 1 << 30;
        for (int i = 0; i < 32; ++i) {
            double v = dred[q * 32 + i];
            int kk = ired[q * 32 + i];
            if (v > BV || (v == BV && kk < BKi)) { BV = v; BKi = kk; }
        }
        idx_out[b * QLEN + q0 + q] = (float)BKi;
    }
}

// =====================================================================
// Kernel 3: in-place output projection  IO = IO @ Wo^T + bo
//   Each block owns 16 rows: stages them to LDS first, so the in-place
//   overwrite is race-free (no block reads another block's rows).
// =====================================================================
#define OPROWS 16

__global__ __launch_bounds__(512, 2)
void outproj_kernel(float* __restrict__ IO, const float* __restrict__ Wo,
                    const float* __restrict__ bo)
{
    __shared__ float ctxs[OPROWS][DIM];    // 64 KB
    __shared__ float wos[64][129];         // 33 KB, +1 pad

    const int m0 = blockIdx.x * OPROWS;
    const int tid = threadIdx.x;
    const int q = tid >> 5, kt = tid & 31;

    #pragma unroll
    for (int p = 0; p < 8; ++p) {          // 4096 float4
        int f4 = tid + p * 512;
        int row = f4 >> 8;                 // 256 float4 per 1024-float row
        int c4 = (f4 & 255) << 2;
        *(float4*)&ctxs[row][c4] = *(const float4*)&IO[(size_t)(m0 + row) * DIM + c4];
    }
    __syncthreads();

    #pragma unroll 1
    for (int oc = 0; oc < DIM / 64; ++oc) {          // 16 chunks of 64 outputs
        float a0 = 0.f, a1 = 0.f;
        #pragma unroll 1
        for (int d0 = 0; d0 < DIM; d0 += 128) {      // 8 K-chunks
            #pragma unroll
            for (int p = 0; p < 4; ++p) {            // stage Wo [64 o][128 d]
                int f4 = tid + p * 512;
                int row = f4 >> 5, c4 = (f4 & 31) << 2;
                float4 wv = *(const float4*)&Wo[(size_t)(oc * 64 + row) * DIM + d0 + c4];
                wos[row][c4] = wv.x; wos[row][c4+1] = wv.y; wos[row][c4+2] = wv.z; wos[row][c4+3] = wv.w;
            }
            __syncthreads();
            #pragma unroll 8
            for (int dd = 0; dd < 128; ++dd) {
                float cv = ctxs[q][d0 + dd];
                a0 = fmaf(cv, wos[kt][dd],      a0);
                a1 = fmaf(cv, wos[32 + kt][dd], a1);
            }
            __syncthreads();
        }
        int o0 = oc * 64 + kt;
        IO[(size_t)(m0 + q) * DIM + o0]      = a0 + bo[o0];
        IO[(size_t)(m0 + q) * DIM + o0 + 32] = a1 + bo[o0 + 32];
    }
}

// =====================================================================
extern "C" void kernel_launch(void* const* d_in, const int* in_sizes, int n_in,
                              void* d_out, int out_size, void* d_ws, size_t ws_size,
                              hipStream_t stream)
{
    (void)in_sizes; (void)n_in; (void)out_size; (void)ws_size;
    const float* query = (const float*)d_in[0];
    const int*   mask  = (const int*)  d_in[1];
    const float* Wq = (const float*)d_in[2];
    const float* bq = (const float*)d_in[3];
    const float* Wk = (const float*)d_in[4];
    const float* bk = (const float*)d_in[5];
    const float* Wv = (const float*)d_in[6];
    const float* bv = (const float*)d_in[7];
    const float* Wo = (const float*)d_in[8];
    const float* bo = (const float*)d_in[9];

    float* out = (float*)d_out;
    const size_t NTOK = (size_t)BS * QLEN;     // 8192
    float* Qw = (float*)d_ws;                  // ws: 3 x 32 MB = 96 MB
    float* Kw = Qw + NTOK * DIM;
    float* Vw = Kw + NTOK * DIM;

    dim3 gemm_grid(DIM / GBN, (BS * QLEN) / GBM);   // (16, 128)
    // Q,K: f64 accumulation (argmax-critical); V: f32. Q pre-scaled by 1/sqrt(dh).
    qkv_gemm<true><<<gemm_grid, dim3(256), 0, stream>>>(query, Wq, bq, Qw, 0.125f);
    qkv_gemm<true><<<gemm_grid, dim3(256), 0, stream>>>(query, Wk, bk, Kw, 1.0f);
    qkv_gemm<false><<<gemm_grid, dim3(256), 0, stream>>>(query, Wv, bv, Vw, 1.0f);

    float* ctx = out;                  // reuse out region as ctx scratch
    float* idx = out + NTOK * DIM;     // argmax output tail
    attn_kernel<<<dim3(QLEN / QT, BS), dim3(512), 0, stream>>>(Qw, Kw, Vw, mask, ctx, idx);

    outproj_kernel<<<dim3(NTOK / OPROWS), dim3(512), 0, stream>>>(out, Wo, bo);
}

// Round 2
// 15459.256 us; speedup vs baseline: 1.4303x; 1.4303x over previous
//
#include <hip/hip_runtime.h>
#include <math.h>
#include <type_traits>

#define BS   4
#define QLEN 2048
#define DIM  1024
#define NH   16
#define DH   64

// =====================================================================
// Kernel 1: projection GEMM  Out = (X @ W^T + bias) * scale
//   X: [8192,1024] row-major, W: [1024,1024] row-major (out-feature major)
//   Output written in [b, h, s, dh] layout for the attention kernel.
//   F64: accumulate in double (precision-critical Q/K path).
// =====================================================================
#define GBM 64
#define GBN 64
#define GBK 32

template<bool F64>
__global__ __launch_bounds__(256)
void qkv_gemm(const float* __restrict__ X, const float* __restrict__ W,
              const float* __restrict__ bias, float* __restrict__ Out,
              float scale)
{
    using acc_t = typename std::conditional<F64, double, float>::type;
    __shared__ float xs[GBM][GBK + 1];   // +1 pad: conflict-free micro-tile reads
    __shared__ float wsm[GBN][GBK + 1];

    const int m0 = blockIdx.y * GBM;
    const int n0 = blockIdx.x * GBN;
    const int tid = threadIdx.x;
    const int tx = tid & 15, ty = tid >> 4;

    acc_t acc[4][4];
    #pragma unroll
    for (int i = 0; i < 4; ++i)
        #pragma unroll
        for (int j = 0; j < 4; ++j) acc[i][j] = (acc_t)0;

    for (int k0 = 0; k0 < DIM; k0 += GBK) {
        #pragma unroll
        for (int p = 0; p < 2; ++p) {
            int f4 = tid + p * 256;            // 512 float4 per tile
            int row = f4 >> 3;                 // 8 float4 per 32-float row
            int c4 = (f4 & 7) << 2;
            float4 xv = *(const float4*)&X[(size_t)(m0 + row) * DIM + k0 + c4];
            xs[row][c4] = xv.x; xs[row][c4+1] = xv.y; xs[row][c4+2] = xv.z; xs[row][c4+3] = xv.w;
            float4 wv = *(const float4*)&W[(size_t)(n0 + row) * DIM + k0 + c4];
            wsm[row][c4] = wv.x; wsm[row][c4+1] = wv.y; wsm[row][c4+2] = wv.z; wsm[row][c4+3] = wv.w;
        }
        __syncthreads();
        #pragma unroll
        for (int kk = 0; kk < GBK; ++kk) {
            float a[4], bb[4];
            #pragma unroll
            for (int i = 0; i < 4; ++i) a[i] = xs[ty * 4 + i][kk];
            #pragma unroll
            for (int j = 0; j < 4; ++j) bb[j] = wsm[tx * 4 + j][kk];
            if (F64) {
                #pragma unroll
                for (int i = 0; i < 4; ++i)
                    #pragma unroll
                    for (int j = 0; j < 4; ++j)
                        acc[i][j] = (acc_t)fma((double)a[i], (double)bb[j], (double)acc[i][j]);
            } else {
                #pragma unroll
                for (int i = 0; i < 4; ++i)
                    #pragma unroll
                    for (int j = 0; j < 4; ++j)
                        acc[i][j] = (acc_t)fmaf(a[i], bb[j], (float)acc[i][j]);
            }
        }
        __syncthreads();
    }

    // epilogue: bias + scale, write in [b,h,s,dh] layout
    #pragma unroll
    for (int i = 0; i < 4; ++i) {
        int row = m0 + ty * 4 + i;
        int b_ = row >> 11;          // / 2048
        int s_ = row & 2047;
        int col0 = n0 + tx * 4;
        int h_ = col0 >> 6, d_ = col0 & 63;
        float4 o;
        #pragma unroll
        for (int j = 0; j < 4; ++j) {
            acc_t v = (acc[i][j] + (acc_t)bias[col0 + j]) * (acc_t)scale;
            (&o.x)[j] = (float)v;
        }
        *(float4*)&Out[((size_t)((b_ * NH + h_) * QLEN + s_)) * DH + d_] = o;
    }
}

// =====================================================================
// Kernel 2: fused attention core.
//   One block = (batch b, 16 query rows), 512 threads = (q 0..15) x (kt 0..31).
//   Loops all 16 heads; per head: pass1 online (max, sumexp) streaming K
//   through LDS chunks of 128 rows, reduce, pass2 recompute scores ->
//   weights -> PV; ctx written to global (reuses d_out's out region).
//   Head-summed weights in f32 REGISTERS (64 VGPRs; f64 spilled to scratch
//   under the old launch_bounds(512,2) 128-VGPR cap -> 42 GB HBM traffic).
//   Numerics: top-2 gap of head-summed weights ~2.6e-2 rel; f32 16-add
//   accumulation error ~1e-8 rel -> no argmax risk.
// =====================================================================
#define QT  16
#define KC  128
#define NCH (QLEN / KC)   // 16

__global__ __launch_bounds__(512, 1)   // allow 256 VGPR: asum must stay in regs
void attn_kernel(const float* __restrict__ Qm, const float* __restrict__ Km,
                 const float* __restrict__ Vm, const int* __restrict__ mask,
                 float* __restrict__ ctx_out, float* __restrict__ idx_out)
{
    __shared__ float qs[QT][DH];                  //  4 KB
    __shared__ float ks[KC][DH + 1];              // 33 KB (+1: conflict-free score reads)
    __shared__ float vs[KC][DH];                  // 32 KB (lane-varies-d -> no pad needed)
    __shared__ __align__(8) float wch[QT][KC];    //  8 KB weights; overlaid reduce scratch
    __shared__ int   msk[KC];
    __shared__ float mq[QT];
    __shared__ float Lq[QT];

    double* dred = (double*)&wch[0][0];           // 512 doubles  @ [0,4096)
    float*  fred = (float*)&wch[8][0];            // 512 floats   @ [4096,6144)
    int*    ired = (int*)&wch[8][0];              // argmax idx overlay

    const int b   = blockIdx.y;
    const int q0  = blockIdx.x * QT;
    const int tid = threadIdx.x;
    const int q   = tid >> 5;        // 0..15
    const int kt  = tid & 31;        // 0..31

    // head-summed softmax weights, thread slot r=(c*4+jj) -> k = c*128 + jj*32 + kt
    float asum[64];
    #pragma unroll
    for (int r = 0; r < 64; ++r) asum[r] = 0.0f;

    #pragma unroll 1
    for (int h = 0; h < NH; ++h) {
        const float* Qh = Qm + (((size_t)b * NH + h) * QLEN + q0) * DH;
        const float* Kh = Km + ((size_t)b * NH + h) * QLEN * DH;
        const float* Vh = Vm + ((size_t)b * NH + h) * QLEN * DH;

        {   // stage q-tile 16x64 (already includes 1/sqrt(dh))
            int i2 = tid << 1;
            int row = i2 >> 6, col = i2 & 63;
            *(float2*)&qs[row][col] = *(const float2*)&Qh[(size_t)row * DH + col];
        }

        // ---------------- pass 1: per-row running (max, sumexp) ----------------
        float  m = -INFINITY;
        double l = 0.0;
        #pragma unroll 1
        for (int c = 0; c < NCH; ++c) {
            #pragma unroll
            for (int p = 0; p < 4; ++p) {
                int f4 = tid + p * 512;
                int row = f4 >> 4, c4 = (f4 & 15) << 2;
                float4 kv = *(const float4*)&Kh[(size_t)(c * KC + row) * DH + c4];
                ks[row][c4] = kv.x; ks[row][c4+1] = kv.y; ks[row][c4+2] = kv.z; ks[row][c4+3] = kv.w;
            }
            if (tid < KC) msk[tid] = mask[b * QLEN + c * KC + tid];
            __syncthreads();

            float sacc[4] = {0.f, 0.f, 0.f, 0.f};
            #pragma unroll
            for (int d0 = 0; d0 < DH; d0 += 8) {
                float qr[8];
                #pragma unroll
                for (int dd = 0; dd < 8; ++dd) qr[dd] = qs[q][d0 + dd];
                #pragma unroll
                for (int jj = 0; jj < 4; ++jj)
                    #pragma unroll
                    for (int dd = 0; dd < 8; ++dd)
                        sacc[jj] = fmaf(qr[dd], ks[kt + 32 * jj][d0 + dd], sacc[jj]);
            }
            #pragma unroll
            for (int jj = 0; jj < 4; ++jj) {
                float s = msk[kt + 32 * jj] ? sacc[jj] : -INFINITY;
                if (s > m)              { l = l * (double)__expf(m - s) + 1.0; m = s; }
                else if (s > -INFINITY) { l += (double)__expf(s - m); }
            }
            __syncthreads();
        }

        // reduce (m,l) across the 32 kt-threads of each q-row
        dred[q * 32 + kt] = l;
        fred[q * 32 + kt] = m;
        __syncthreads();
        if (kt == 0) {
            float M = -INFINITY;
            for (int i = 0; i < 32; ++i) M = fmaxf(M, fred[q * 32 + i]);
            double L = 0.0;
            for (int i = 0; i < 32; ++i) {
                float mi = fred[q * 32 + i];
                if (mi > -INFINITY) L += dred[q * 32 + i] * exp((double)(mi - M));
            }
            mq[q] = M;
            Lq[q] = (float)L;
        }
        __syncthreads();

        // ---------------- pass 2: weights -> asum (f32 regs) -> PV ----------------
        float cv0 = 0.f, cv1 = 0.f;
        const float Mv = mq[q], Lv = Lq[q];
        #pragma unroll
        for (int c = 0; c < NCH; ++c) {
            #pragma unroll
            for (int p = 0; p < 4; ++p) {
                int f4 = tid + p * 512;
                int row = f4 >> 4, c4 = (f4 & 15) << 2;
                float4 kv = *(const float4*)&Kh[(size_t)(c * KC + row) * DH + c4];
                ks[row][c4] = kv.x; ks[row][c4+1] = kv.y; ks[row][c4+2] = kv.z; ks[row][c4+3] = kv.w;
                *(float4*)&vs[row][c4] = *(const float4*)&Vh[(size_t)(c * KC + row) * DH + c4];
            }
            if (tid < KC) msk[tid] = mask[b * QLEN + c * KC + tid];
            __syncthreads();

            float sacc[4] = {0.f, 0.f, 0.f, 0.f};
            #pragma unroll
            for (int d0 = 0; d0 < DH; d0 += 8) {
                float qr[8];
                #pragma unroll
                for (int dd = 0; dd < 8; ++dd) qr[dd] = qs[q][d0 + dd];
                #pragma unroll
                for (int jj = 0; jj < 4; ++jj)
                    #pragma unroll
                    for (int dd = 0; dd < 8; ++dd)
                        sacc[jj] = fmaf(qr[dd], ks[kt + 32 * jj][d0 + dd], sacc[jj]);
            }
            #pragma unroll
            for (int jj = 0; jj < 4; ++jj) {
                float s = msk[kt + 32 * jj] ? sacc[jj] : -INFINITY;
                float w = expf(s - Mv) / Lv;          // accurate exp + true division
                wch[q][kt + 32 * jj] = w;
                asum[c * 4 + jj] += w;                // static index: c-loop fully unrolled
            }
            __syncthreads();

            #pragma unroll 8
            for (int k = 0; k < KC; ++k) {
                float w = wch[q][k];
                cv0 = fmaf(w, vs[k][kt],      cv0);
                cv1 = fmaf(w, vs[k][kt + 32], cv1);
            }
            __syncthreads();
        }
        float* cp = ctx_out + ((size_t)(b * QLEN + q0 + q)) * DIM + h * DH;
        cp[kt]      = cv0;
        cp[kt + 32] = cv1;
    }

    // ---------------- argmax of head-summed weights (first-index ties) ------
    float bv = -1.0f; int bk_ = 0;
    #pragma unroll
    for (int r = 0; r < 64; ++r) {   // k strictly increasing in r -> '>' keeps first
        int k = (r >> 2) * KC + (r & 3) * 32 + kt;
        if (asum[r] > bv) { bv = asum[r]; bk_ = k; }
    }
    __syncthreads();
    dred[q * 32 + kt] = (double)bv;
    ired[q * 32 + kt] = bk_;
    __syncthreads();
    if (kt == 0) {
        double BV = -1.0; int BKi = 1 << 30;
        for (int i = 0; i < 32; ++i) {
            double v = dred[q * 32 + i];
            int kk = ired[q * 32 + i];
            if (v > BV || (v == BV && kk < BKi)) { BV = v; BKi = kk; }
        }
        idx_out[b * QLEN + q0 + q] = (float)BKi;
    }
}

// =====================================================================
// Kernel 3: in-place output projection  IO = IO @ Wo^T + bo
//   Each block owns 16 rows: stages them to LDS first, so the in-place
//   overwrite is race-free (no block reads another block's rows).
// =====================================================================
#define OPROWS 16

__global__ __launch_bounds__(512, 2)
void outproj_kernel(float* __restrict__ IO, const float* __restrict__ Wo,
                    const float* __restrict__ bo)
{
    __shared__ float ctxs[OPROWS][DIM];    // 64 KB
    __shared__ float wos[64][129];         // 33 KB, +1 pad

    const int m0 = blockIdx.x * OPROWS;
    const int tid = threadIdx.x;
    const int q = tid >> 5, kt = tid & 31;

    #pragma unroll
    for (int p = 0; p < 8; ++p) {          // 4096 float4
        int f4 = tid + p * 512;
        int row = f4 >> 8;                 // 256 float4 per 1024-float row
        int c4 = (f4 & 255) << 2;
        *(float4*)&ctxs[row][c4] = *(const float4*)&IO[(size_t)(m0 + row) * DIM + c4];
    }
    __syncthreads();

    #pragma unroll 1
    for (int oc = 0; oc < DIM / 64; ++oc) {          // 16 chunks of 64 outputs
        float a0 = 0.f, a1 = 0.f;
        #pragma unroll 1
        for (int d0 = 0; d0 < DIM; d0 += 128) {      // 8 K-chunks
            #pragma unroll
            for (int p = 0; p < 4; ++p) {            // stage Wo [64 o][128 d]
                int f4 = tid + p * 512;
                int row = f4 >> 5, c4 = (f4 & 31) << 2;
                float4 wv = *(const float4*)&Wo[(size_t)(oc * 64 + row) * DIM + d0 + c4];
                wos[row][c4] = wv.x; wos[row][c4+1] = wv.y; wos[row][c4+2] = wv.z; wos[row][c4+3] = wv.w;
            }
            __syncthreads();
            #pragma unroll 8
            for (int dd = 0; dd < 128; ++dd) {
                float cv = ctxs[q][d0 + dd];
                a0 = fmaf(cv, wos[kt][dd],      a0);
                a1 = fmaf(cv, wos[32 + kt][dd], a1);
            }
            __syncthreads();
        }
        int o0 = oc * 64 + kt;
        IO[(size_t)(m0 + q) * DIM + o0]      = a0 + bo[o0];
        IO[(size_t)(m0 + q) * DIM + o0 + 32] = a1 + bo[o0 + 32];
    }
}

// =====================================================================
extern "C" void kernel_launch(void* const* d_in, const int* in_sizes, int n_in,
                              void* d_out, int out_size, void* d_ws, size_t ws_size,
                              hipStream_t stream)
{
    (void)in_sizes; (void)n_in; (void)out_size; (void)ws_size;
    const float* query = (const float*)d_in[0];
    const int*   mask  = (const int*)  d_in[1];
    const float* Wq = (const float*)d_in[2];
    const float* bq = (const float*)d_in[3];
    const float* Wk = (const float*)d_in[4];
    const float* bk = (const float*)d_in[5];
    const float* Wv = (const float*)d_in[6];
    const float* bv = (const float*)d_in[7];
    const float* Wo = (const float*)d_in[8];
    const float* bo = (const float*)d_in[9];

    float* out = (float*)d_out;
    const size_t NTOK = (size_t)BS * QLEN;     // 8192
    float* Qw = (float*)d_ws;                  // ws: 3 x 32 MB = 96 MB
    float* Kw = Qw + NTOK * DIM;
    float* Vw = Kw + NTOK * DIM;

    dim3 gemm_grid(DIM / GBN, (BS * QLEN) / GBM);   // (16, 128)
    // Q,K: f64 accumulation (argmax-critical); V: f32. Q pre-scaled by 1/sqrt(dh).
    qkv_gemm<true><<<gemm_grid, dim3(256), 0, stream>>>(query, Wq, bq, Qw, 0.125f);
    qkv_gemm<true><<<gemm_grid, dim3(256), 0, stream>>>(query, Wk, bk, Kw, 1.0f);
    qkv_gemm<false><<<gemm_grid, dim3(256), 0, stream>>>(query, Wv, bv, Vw, 1.0f);

    float* ctx = out;                  // reuse out region as ctx scratch
    float* idx = out + NTOK * DIM;     // argmax output tail
    attn_kernel<<<dim3(QLEN / QT, BS), dim3(512), 0, stream>>>(Qw, Kw, Vw, mask, ctx, idx);

    outproj_kernel<<<dim3(NTOK / OPROWS), dim3(512), 0, stream>>>(out, Wo, bo);
}